// Round 14
// baseline (264.259 us; speedup 1.0000x reference)
//
#include <hip/hip_runtime.h>
#include <stdint.h>

#define HIDDEN 1024
#define SEQ 4096
#define BATCH 4
#define HEADS 16
#define HDIM 64
#define M_TOT (BATCH * SEQ)   // 16384
#define NCH 4                 // split-S chunks for kv reduction
#define NT 16                 // K-steps of 64 in projection GEMMs

typedef __bf16 bf16x8 __attribute__((ext_vector_type(8)));
typedef float f32x4 __attribute__((ext_vector_type(4)));
typedef unsigned short u16x8 __attribute__((ext_vector_type(8)));

static __device__ __forceinline__ unsigned short f2bf(float f) {
  union { float f; uint32_t u; } v; v.f = f;
  uint32_t u = v.u;
  uint32_t r = (u + 0x7fffu + ((u >> 16) & 1u)) >> 16;
  return (unsigned short)r;
}
static __device__ __forceinline__ void load_lds16(const void* g, void* l) {
  __builtin_amdgcn_global_load_lds(
      (__attribute__((address_space(1))) void*)(g),
      (__attribute__((address_space(3))) void*)(l), 16, 0, 0);
}

// ---------------- fused prep kernel ----------------
__global__ __launch_bounds__(256) void prep_k(
    const float* __restrict__ x, unsigned short* __restrict__ xb,
    const float* __restrict__ Wk, const float* __restrict__ Wv,
    const float* __restrict__ Wq,
    unsigned short* __restrict__ Bt, unsigned short* __restrict__ Wqt,
    const float* __restrict__ bk, const float* __restrict__ bv,
    float* __restrict__ bkv,
    const float* __restrict__ mask, float* __restrict__ norm) {
  const int bid = blockIdx.x;
  const int tid = threadIdx.x;
  __shared__ float ts[64][65];
  if (bid < 8192) {
    int idx = bid * 256 + tid;
    const float4* xv = (const float4*)x;
    float4 a = xv[(size_t)idx * 2];
    float4 b = xv[(size_t)idx * 2 + 1];
    u16x8 o;
    o[0] = f2bf(a.x); o[1] = f2bf(a.y); o[2] = f2bf(a.z); o[3] = f2bf(a.w);
    o[4] = f2bf(b.x); o[5] = f2bf(b.y); o[6] = f2bf(b.z); o[7] = f2bf(b.w);
    *(u16x8*)(xb + (size_t)idx * 8) = o;
  } else if (bid < 8960) {
    int idx = bid - 8192;
    int z = idx >> 8, rem = idx & 255;
    const float* W = (z == 0) ? Wk : (z == 1) ? Wv : Wq;
    unsigned short* out = (z == 2) ? Wqt : (Bt + (size_t)z * HIDDEN * HIDDEN);
    int n0 = (rem & 15) * 64, k0 = (rem >> 4) * 64;
    int c = tid & 63, rq = tid >> 6;
    for (int i = 0; i < 16; ++i) {
      int r = i * 4 + rq;
      ts[r][c] = W[(size_t)(k0 + r) * HIDDEN + n0 + c];
    }
    __syncthreads();
    for (int i = 0; i < 16; ++i) {
      int n = i * 4 + rq;
      out[(size_t)(n0 + n) * HIDDEN + k0 + c] = f2bf(ts[c][n]);
    }
  } else if (bid < 8968) {
    int i = (bid - 8960) * 256 + tid;
    bkv[i] = (i < HIDDEN) ? bk[i] : bv[i - HIDDEN];
  } else {
    int b = bid - 8968;
    float s = 0.f;
    for (int i = tid; i < SEQ; i += 256) s += mask[b * SEQ + i];
    for (int off = 32; off; off >>= 1) s += __shfl_down(s, off);
    __shared__ float wsum[4];
    if ((tid & 63) == 0) wsum[tid >> 6] = s;
    __syncthreads();
    if (tid == 0) {
      float t = wsum[0] + wsum[1] + wsum[2] + wsum[3];
      norm[b] = rsqrtf(t * (float)HDIM);
    }
  }
}

// ---------------- 128x128 GEMM: A via LDS (dbuf), B DIRECT FROM GLOBAL (L2-hot) -------
// C[row][n] = sum_k A[row][k]*Bt[n][k] + bias[n], then * mask[row].
// OUT_MODE 2: bf16 transposed KVt[(n*4+b)*4096+s].  OUT_MODE 4: fused q@kv_head -> f32.
// 4 waves (2M x 2N), wave-tile 64x64. Per block-K-tile: only 32 KB LDS reads (A),
// B-frags are 8 global b128/wave from the L2-resident Bt panel (immutable -> no hazard).
// K-loop skeleton = R13's proven race-free pattern (stage t+1, read t, MFMA, vmcnt(0), bar).
template <int OUT_MODE>
__global__ __launch_bounds__(256, 2) void gemm128_k(
    const unsigned short* __restrict__ A, const unsigned short* __restrict__ Bt,
    const float* __restrict__ bias, const float* __restrict__ mask,
    const unsigned short* __restrict__ kvt,
    void* __restrict__ C, int nbn) {
  __shared__ unsigned short smem[16384];  // 32 KiB: 2 bufs x (A 128x64) ; reused by epilogue

  const int nwg = gridDim.x;
  const int bid = blockIdx.x;
  const int wg = (bid & 7) * (nwg >> 3) + (bid >> 3);  // XCD swizzle (nwg%8==0)
  const int row0 = (wg / nbn) * 128;
  const int col0 = (wg % nbn) * 128;

  const int tid = threadIdx.x;
  const int wave = tid >> 6;
  const int lane = tid & 63;
  const int wm = wave >> 1;   // 0..1 (64-row band)
  const int wn = wave & 1;    // 0..1 (64-col band)
  const int lr = lane & 15;
  const int hi = lane >> 4;   // 0..3

  // A staging: linear LDS dest, inverse-swizzled global source (chunk ^= row&7)
  const int sr = tid >> 3;                          // 0..31 (row within 32-row group)
  const int sc = ((tid & 7) ^ (sr & 7)) * 8;        // XORed 16B chunk
  const unsigned short* sA = A + (size_t)(row0 + sr) * HIDDEN + sc;

#define STAGE_A(tt) { int dst_ = ((tt) & 1) * 8192 + tid * 8; \
    const unsigned short* s_ = sA + (size_t)(tt) * 64; \
    load_lds16(s_,                          &smem[dst_]); \
    load_lds16(s_ + (size_t)32 * HIDDEN,    &smem[dst_ + 2048]); \
    load_lds16(s_ + (size_t)64 * HIDDEN,    &smem[dst_ + 4096]); \
    load_lds16(s_ + (size_t)96 * HIDDEN,    &smem[dst_ + 6144]); }

  // A frag read: row ra=wm*64+rf*16+lr -> ra*64 + ((kc ^ (ra&7))*8); ra&7 == lr&7
  const int chunk0 = (hi ^ (lr & 7)) * 8;          // kh=0
  const int chunk1 = ((4 + hi) ^ (lr & 7)) * 8;    // kh=1
  const int aoff = (wm * 64 + lr) * 64;            // + rf*1024

  // B global row pointers (per cf), k-offset added per tile
  const unsigned short* Brow[4];
#pragma unroll
  for (int cf = 0; cf < 4; ++cf)
    Brow[cf] = Bt + (size_t)(col0 + wn * 64 + cf * 16 + lr) * HIDDEN + hi * 8;

  f32x4 acc[4][4];
#pragma unroll
  for (int i = 0; i < 4; ++i)
#pragma unroll
    for (int j = 0; j < 4; ++j) acc[i][j] = (f32x4){0.f, 0.f, 0.f, 0.f};

  // prologue: stage A(0); load B(0); drain; barrier
  STAGE_A(0)
  bf16x8 b0[4][2], b1[4][2];
#pragma unroll
  for (int cf = 0; cf < 4; ++cf) {
    b0[cf][0] = *(const bf16x8*)&Brow[cf][0];
    b0[cf][1] = *(const bf16x8*)&Brow[cf][32];
  }
  asm volatile("s_waitcnt vmcnt(0)" ::: "memory");
  __builtin_amdgcn_s_barrier();

#define BODY(T, BC, BN) { \
    const int bb_ = ((T) & 1) * 8192; \
    if ((T) + 1 < NT) STAGE_A((T) + 1) \
    if ((T) + 1 < NT) { \
      _Pragma("unroll") \
      for (int cf = 0; cf < 4; ++cf) { \
        BN[cf][0] = *(const bf16x8*)&Brow[cf][((T) + 1) * 64]; \
        BN[cf][1] = *(const bf16x8*)&Brow[cf][((T) + 1) * 64 + 32]; \
      } \
    } \
    bf16x8 af_[4][2]; \
    _Pragma("unroll") \
    for (int rf = 0; rf < 4; ++rf) { \
      af_[rf][0] = *(const bf16x8*)&smem[bb_ + aoff + rf * 1024 + chunk0]; \
      af_[rf][1] = *(const bf16x8*)&smem[bb_ + aoff + rf * 1024 + chunk1]; \
    } \
    __builtin_amdgcn_s_setprio(1); \
    _Pragma("unroll") \
    for (int rf = 0; rf < 4; ++rf) \
      _Pragma("unroll") \
      for (int cf = 0; cf < 4; ++cf) \
        _Pragma("unroll") \
        for (int kh = 0; kh < 2; ++kh) \
          acc[rf][cf] = __builtin_amdgcn_mfma_f32_16x16x32_bf16(af_[rf][kh], BC[cf][kh], acc[rf][cf], 0, 0, 0); \
    __builtin_amdgcn_s_setprio(0); \
    asm volatile("s_waitcnt vmcnt(0)" ::: "memory"); \
    __builtin_amdgcn_s_barrier(); }

  for (int tp = 0; tp < NT / 2; ++tp) {
    BODY(2 * tp, b0, b1)
    BODY(2 * tp + 1, b1, b0)
  }
#undef BODY

  // ---- epilogue (R13-verified forms, single 64x64 per wave) ----
  float bcol[4];
#pragma unroll
  for (int cf = 0; cf < 4; ++cf)
    bcol[cf] = bias[col0 + wn * 64 + cf * 16 + lr];

  unsigned short* wt = &smem[wave * 4096];  // per-wave 64x64 bf16 (8 KiB)

  if (OUT_MODE == 2) {
    // transposed bf16 store: KVt[(n*4+b)*4096 + s]
    const int b = row0 >> 12;
    const int s0 = (row0 & 4095) + wm * 64;
    unsigned short* KVt = (unsigned short*)C;
#pragma unroll
    for (int rf = 0; rf < 4; ++rf)
#pragma unroll
      for (int j = 0; j < 4; ++j) {
        int r = rf * 16 + hi * 4 + j;  // 0..63
        float mrow = mask[row0 + wm * 64 + r];
#pragma unroll
        for (int cf = 0; cf < 4; ++cf) {
          int c = cf * 16 + lr;
          wt[c * 64 + (r ^ ((c & 7) << 3))] = f2bf((acc[rf][cf][j] + bcol[cf]) * mrow);
        }
      }
    asm volatile("s_waitcnt lgkmcnt(0)" ::: "memory");
#pragma unroll
    for (int i = 0; i < 8; ++i) {
      int flat = i * 64 + lane;
      int c = flat >> 3, rq = flat & 7;
      uint4 vv = *(const uint4*)&wt[c * 64 + ((rq * 8) ^ ((c & 7) << 3))];
      *(uint4*)&KVt[((size_t)(col0 + wn * 64 + c) * 4 + b) * 4096 + s0 + rq * 8] = vv;
    }
    asm volatile("s_waitcnt lgkmcnt(0)" ::: "memory");
  } else {
    // OUT_MODE 4: fused q @ kv_head -> f32 out
    float* Og = (float*)C;
    const int b = row0 >> 12;
    const int bh = b * 16 + (col0 >> 6) + wn;  // this wave's head
    bf16x8 kvf[4][2];
#pragma unroll
    for (int et = 0; et < 4; ++et) {
      kvf[et][0] = *(const bf16x8*)&kvt[(size_t)bh * 4096 + (et * 16 + lr) * 64 + hi * 8];
      kvf[et][1] = *(const bf16x8*)&kvt[(size_t)bh * 4096 + (et * 16 + lr) * 64 + 32 + hi * 8];
    }
#pragma unroll
    for (int rf = 0; rf < 4; ++rf)
#pragma unroll
      for (int j = 0; j < 4; ++j) {
        int r = rf * 16 + hi * 4 + j;
        float mrow = mask[row0 + wm * 64 + r];
#pragma unroll
        for (int cf = 0; cf < 4; ++cf) {
          int c = cf * 16 + lr;
          wt[r * 64 + (c ^ ((r & 7) << 3))] = f2bf((acc[rf][cf][j] + bcol[cf]) * mrow);
        }
      }
    asm volatile("s_waitcnt lgkmcnt(0)" ::: "memory");
    const int echunk0 = (hi ^ (lr & 7)) * 8;
    const int echunk1 = ((4 + hi) ^ (lr & 7)) * 8;
#pragma unroll
    for (int g = 0; g < 4; ++g) {
      bf16x8 a0 = *(const bf16x8*)&wt[(g * 16 + lr) * 64 + echunk0];
      bf16x8 a1 = *(const bf16x8*)&wt[(g * 16 + lr) * 64 + echunk1];
#pragma unroll
      for (int et = 0; et < 4; ++et) {
        f32x4 o4 = (f32x4){0.f, 0.f, 0.f, 0.f};
        o4 = __builtin_amdgcn_mfma_f32_16x16x32_bf16(a0, kvf[et][0], o4, 0, 0, 0);
        o4 = __builtin_amdgcn_mfma_f32_16x16x32_bf16(a1, kvf[et][1], o4, 0, 0, 0);
#pragma unroll
        for (int j = 0; j < 4; ++j)
          __builtin_nontemporal_store(o4[j],
              &Og[(size_t)(row0 + wm * 64 + g * 16 + hi * 4 + j) * 1024
                  + col0 + wn * 64 + et * 16 + lr]);
      }
    }
    asm volatile("s_waitcnt lgkmcnt(0)" ::: "memory");
  }
#undef STAGE_A
}

// ---------------- kv partials via MFMA: part[ch][bh][d][e] = sum_s Kt[d][s]*Vt[e][s] ----
__global__ __launch_bounds__(256) void kvpart2_k(const unsigned short* __restrict__ KVt,
                                                 float* __restrict__ part) {
  const int bh = blockIdx.x, ch = blockIdx.y;
  const int b = bh >> 4, h = bh & 15;
  __shared__ unsigned short tl[32768];  // 4 bufs x (A[64][64] + B[64][64]) = 64 KiB
  const int tid = threadIdx.x;
  const int wave = tid >> 6, lane = tid & 63;
  const int lr = lane & 15, hi = lane >> 4;

  const int r0 = tid >> 3;
  const int cc0 = ((tid & 7) ^ (r0 & 7)) * 8;
  const int r1 = 32 + r0;
  const int cc1 = ((tid & 7) ^ (r1 & 7)) * 8;
  const unsigned short* A0 = KVt + ((size_t)(h * 64 + r0) * 4 + b) * 4096 + ch * 1024 + cc0;
  const unsigned short* A1 = KVt + ((size_t)(h * 64 + r1) * 4 + b) * 4096 + ch * 1024 + cc1;
  const unsigned short* B0 = KVt + ((size_t)(1024 + h * 64 + r0) * 4 + b) * 4096 + ch * 1024 + cc0;
  const unsigned short* B1 = KVt + ((size_t)(1024 + h * 64 + r1) * 4 + b) * 4096 + ch * 1024 + cc1;

#define KSTAGE(tt) { int bb2 = ((tt) & 3) * 8192; \
    load_lds16(A0 + (tt) * 64, &tl[bb2 + tid * 8]); \
    load_lds16(A1 + (tt) * 64, &tl[bb2 + 2048 + tid * 8]); \
    load_lds16(B0 + (tt) * 64, &tl[bb2 + 4096 + tid * 8]); \
    load_lds16(B1 + (tt) * 64, &tl[bb2 + 6144 + tid * 8]); }

  const int ra = wave * 16 + lr;
  const int aoff = ra * 64;
  const int ach0 = (hi ^ (ra & 7)) * 8, ach1 = ((4 + hi) ^ (ra & 7)) * 8;

  f32x4 acc4[4];
#pragma unroll
  for (int nt = 0; nt < 4; ++nt) acc4[nt] = (f32x4){0.f, 0.f, 0.f, 0.f};

  KSTAGE(0) KSTAGE(1)
  asm volatile("s_waitcnt vmcnt(4)" ::: "memory");
  __builtin_amdgcn_s_barrier();
  for (int t = 0; t < 16; ++t) {
    const int bb = (t & 3) * 8192;
    if (t + 2 < 16) KSTAGE(t + 2)
    bf16x8 a0 = *(const bf16x8*)&tl[bb + aoff + ach0];
    bf16x8 a1 = *(const bf16x8*)&tl[bb + aoff + ach1];
    bf16x8 bf0[4], bf1[4];
#pragma unroll
    for (int nt = 0; nt < 4; ++nt) {
      int rb = nt * 16 + lr;
      bf0[nt] = *(const bf16x8*)&tl[bb + 4096 + rb * 64 + ((hi ^ (rb & 7)) * 8)];
      bf1[nt] = *(const bf16x8*)&tl[bb + 4096 + rb * 64 + (((4 + hi) ^ (rb & 7)) * 8)];
    }
#pragma unroll
    for (int nt = 0; nt < 4; ++nt) {
      acc4[nt] = __builtin_amdgcn_mfma_f32_16x16x32_bf16(a0, bf0[nt], acc4[nt], 0, 0, 0);
      acc4[nt] = __builtin_amdgcn_mfma_f32_16x16x32_bf16(a1, bf1[nt], acc4[nt], 0, 0, 0);
    }
    if (t < 14) asm volatile("s_waitcnt vmcnt(4)" ::: "memory");
    else        asm volatile("s_waitcnt vmcnt(0)" ::: "memory");
    __builtin_amdgcn_s_barrier();
  }
  float* dst = part + ((size_t)(ch * 64 + bh)) * 4096;
#pragma unroll
  for (int nt = 0; nt < 4; ++nt)
#pragma unroll
    for (int j = 0; j < 4; ++j)
      dst[(wave * 16 + hi * 4 + j) * 64 + nt * 16 + lr] = acc4[nt][j];
#undef KSTAGE
}

// ---------------- reduce + transpose + norm: kvt[bh][e][d] bf16 ----------------
__global__ void kvreduce_k(const float* __restrict__ part, const float* __restrict__ norm,
                           unsigned short* __restrict__ kvt) {
  int idx4 = (blockIdx.x * 256 + threadIdx.x) * 4;  // [bh][e][d0..d0+3]
  int bh = idx4 >> 12, rem = idx4 & 4095;
  int e = rem >> 6, d0 = rem & 63;
  float s0 = 0.f, s1 = 0.f, s2 = 0.f, s3 = 0.f;
#pragma unroll
  for (int ch = 0; ch < NCH; ++ch) {
    const float* p = part + ((size_t)(ch * 64 + bh)) * 4096 + e;  // [d][e] layout
    s0 += p[(d0 + 0) * 64];
    s1 += p[(d0 + 1) * 64];
    s2 += p[(d0 + 2) * 64];
    s3 += p[(d0 + 3) * 64];
  }
  float nb = norm[bh >> 4];
  ushort4 o;
  o.x = f2bf(s0 * nb); o.y = f2bf(s1 * nb); o.z = f2bf(s2 * nb); o.w = f2bf(s3 * nb);
  *(ushort4*)&kvt[idx4] = o;
}

// ---------------- launch ----------------
extern "C" void kernel_launch(void* const* d_in, const int* in_sizes, int n_in,
                              void* d_out, int out_size, void* d_ws, size_t ws_size,
                              hipStream_t stream) {
  const float* x = (const float*)d_in[0];
  const float* mask = (const float*)d_in[1];
  const float* Wq = (const float*)d_in[2];
  const float* bq = (const float*)d_in[3];
  const float* Wk = (const float*)d_in[4];
  const float* bk = (const float*)d_in[5];
  const float* Wv = (const float*)d_in[6];
  const float* bv = (const float*)d_in[7];
  float* out = (float*)d_out;

  char* w = (char*)d_ws;
  unsigned short* xb = (unsigned short*)w;   w += (size_t)M_TOT * HIDDEN * 2;       // 32 MiB
  unsigned short* Bt = (unsigned short*)w;   w += (size_t)2048 * HIDDEN * 2;        // 4 MiB
  unsigned short* Wqt = (unsigned short*)w;  w += (size_t)HIDDEN * HIDDEN * 2;      // 2 MiB
  unsigned short* KVt = (unsigned short*)w;  w += (size_t)2048 * BATCH * SEQ * 2;   // 64 MiB
  float* part = (float*)w;                   w += (size_t)NCH * 64 * 4096 * 4;      // 4 MiB
  unsigned short* kvt = (unsigned short*)w;  w += (size_t)64 * 4096 * 2;            // 0.5 MiB
  float* bkv = (float*)w;                    w += 2048 * 4;
  float* norm = (float*)w;                   w += 64;

  prep_k<<<dim3(8972), dim3(256), 0, stream>>>(x, xb, Wk, Wv, Wq, Bt, Wqt, bk, bv, bkv, mask, norm);
  // KV projection: M=16384, N=2048, tiles 128x128 -> 128*16 = 2048 blocks
  gemm128_k<2><<<dim3(2048), dim3(256), 0, stream>>>(xb, Bt, bkv, mask, nullptr, (void*)KVt, 16);
  kvpart2_k<<<dim3(64, NCH), dim3(256), 0, stream>>>(KVt, part);
  kvreduce_k<<<dim3(256), dim3(256), 0, stream>>>(part, norm, kvt);
  // Fused Q projection + out = q @ kv_head: M=16384, N=1024 -> 128*8 = 1024 blocks
  gemm128_k<4><<<dim3(1024), dim3(256), 0, stream>>>(xb, Wqt, bq, mask, kvt, (void*)out, 8);
}

// Round 15
// 154.404 us; speedup vs baseline: 1.7115x; 1.7115x over previous
//
#include <hip/hip_runtime.h>
#include <stdint.h>

#define HIDDEN 1024
#define SEQ 4096
#define BATCH 4
#define HEADS 16
#define HDIM 64
#define M_TOT (BATCH * SEQ)   // 16384
#define NCH 4                 // split-S chunks for kv reduction
#define NT64 16               // K-steps of 64 in projection GEMMs

typedef __bf16 bf16x8 __attribute__((ext_vector_type(8)));
typedef float f32x4 __attribute__((ext_vector_type(4)));
typedef unsigned short u16x8 __attribute__((ext_vector_type(8)));

static __device__ __forceinline__ unsigned short f2bf(float f) {
  union { float f; uint32_t u; } v; v.f = f;
  uint32_t u = v.u;
  uint32_t r = (u + 0x7fffu + ((u >> 16) & 1u)) >> 16;
  return (unsigned short)r;
}
static __device__ __forceinline__ void load_lds16(const void* g, void* l) {
  __builtin_amdgcn_global_load_lds(
      (__attribute__((address_space(1))) void*)(g),
      (__attribute__((address_space(3))) void*)(l), 16, 0, 0);
}

// ---------------- fused prep kernel ----------------
// [0,8192): x f32->bf16; [8192,8960): transpose Wk/Wv/Wq -> Bt|Wqt;
// [8960,8968): bias concat bk|bv; [8968,8972): mask sum -> norm
__global__ __launch_bounds__(256) void prep_k(
    const float* __restrict__ x, unsigned short* __restrict__ xb,
    const float* __restrict__ Wk, const float* __restrict__ Wv,
    const float* __restrict__ Wq,
    unsigned short* __restrict__ Bt, unsigned short* __restrict__ Wqt,
    const float* __restrict__ bk, const float* __restrict__ bv,
    float* __restrict__ bkv,
    const float* __restrict__ mask, float* __restrict__ norm) {
  const int bid = blockIdx.x;
  const int tid = threadIdx.x;
  __shared__ float ts[64][65];
  if (bid < 8192) {
    int idx = bid * 256 + tid;
    const float4* xv = (const float4*)x;
    float4 a = xv[(size_t)idx * 2];
    float4 b = xv[(size_t)idx * 2 + 1];
    u16x8 o;
    o[0] = f2bf(a.x); o[1] = f2bf(a.y); o[2] = f2bf(a.z); o[3] = f2bf(a.w);
    o[4] = f2bf(b.x); o[5] = f2bf(b.y); o[6] = f2bf(b.z); o[7] = f2bf(b.w);
    *(u16x8*)(xb + (size_t)idx * 8) = o;
  } else if (bid < 8960) {
    int idx = bid - 8192;
    int z = idx >> 8, rem = idx & 255;
    const float* W = (z == 0) ? Wk : (z == 1) ? Wv : Wq;
    unsigned short* out = (z == 2) ? Wqt : (Bt + (size_t)z * HIDDEN * HIDDEN);
    int n0 = (rem & 15) * 64, k0 = (rem >> 4) * 64;
    int c = tid & 63, rq = tid >> 6;
    for (int i = 0; i < 16; ++i) {
      int r = i * 4 + rq;
      ts[r][c] = W[(size_t)(k0 + r) * HIDDEN + n0 + c];
    }
    __syncthreads();
    for (int i = 0; i < 16; ++i) {
      int n = i * 4 + rq;
      out[(size_t)(n0 + n) * HIDDEN + k0 + c] = f2bf(ts[c][n]);
    }
  } else if (bid < 8968) {
    int i = (bid - 8960) * 256 + tid;
    bkv[i] = (i < HIDDEN) ? bk[i] : bv[i - HIDDEN];
  } else {
    int b = bid - 8968;
    float s = 0.f;
    for (int i = tid; i < SEQ; i += 256) s += mask[b * SEQ + i];
    for (int off = 32; off; off >>= 1) s += __shfl_down(s, off);
    __shared__ float wsum[4];
    if ((tid & 63) == 0) wsum[tid >> 6] = s;
    __syncthreads();
    if (tid == 0) {
      float t = wsum[0] + wsum[1] + wsum[2] + wsum[3];
      norm[b] = rsqrtf(t * (float)HDIM);
    }
  }
}

// ---------------- 256x256 GEMM (R6 core) ----------------
// C[row][n] = sum_k A[row][k]*Bt[n][k] + bias[n], then * mask[row].
// OUT_MODE 2: bf16 transposed KVt[(n*4+b)*4096+s].
// OUT_MODE 4: FUSED out = ((xWq+bq)*mask) @ kv_head  -> f32 row-major out.
//   Each wave's 64-col stripe == one head; q restaged to LDS (swizzled),
//   re-read as A-frags, multiplied by kvt head block (B-frags from global).
template <int OUT_MODE>
__global__ __launch_bounds__(512, 2) void gemm256_k(
    const unsigned short* __restrict__ A, const unsigned short* __restrict__ Bt,
    const float* __restrict__ bias, const float* __restrict__ mask,
    const unsigned short* __restrict__ kvt,
    void* __restrict__ C, int nbn) {
  __shared__ unsigned short smem[65536];  // 128 KiB: 2 bufs x (A 256x64 + B 256x64)

  const int nwg = gridDim.x;
  const int bid = blockIdx.x;
  const int wg = (bid & 7) * (nwg >> 3) + (bid >> 3);  // XCD swizzle (nwg%8==0)
  const int row0 = (wg / nbn) * 256;
  const int col0 = (wg % nbn) * 256;

  const int tid = threadIdx.x;
  const int wave = tid >> 6;
  const int lane = tid & 63;
  const int wm = wave >> 2;   // 0..1 (M half)
  const int wn = wave & 3;    // 0..3 (N quarter)
  const int lr = lane & 15;
  const int hi = lane >> 4;   // 0..3

  // staging: linear LDS dest, inverse-swizzled global source (chunk ^= row&7)
  const int srow = tid >> 3;                        // 0..63
  const int scol = ((tid & 7) ^ (srow & 7)) * 8;    // (row&7)-XORed 16B chunk
  const unsigned short* sA = A + (size_t)(row0 + srow) * HIDDEN + scol;
  const unsigned short* sB = Bt + (size_t)(col0 + srow) * HIDDEN + scol;
  const int ldst = tid * 8;

#define STAGE(half, tt, isB) { \
    int dst_ = ((tt)&1) * 32768 + (isB) * 16384 + (half) * 8192 + ldst; \
    const unsigned short* src_ = ((isB) ? sB : sA) + (size_t)(half) * 128 * HIDDEN + (tt) * 64; \
    load_lds16(src_, &smem[dst_]); \
    load_lds16(src_ + (size_t)64 * HIDDEN, &smem[dst_ + 4096]); }

  // swizzled frag read offsets: row ra -> ra*64 + ((k8 ^ (ra&7))*8); ra&7 == lr&7
  const int chunk0 = (hi ^ (lr & 7)) * 8;          // kh=0
  const int chunk1 = ((4 + hi) ^ (lr & 7)) * 8;    // kh=1
  const int arow = (wm * 128 + lr) * 64;           // + rf*1024 (+4096 for m-half 1)
  const int brow = 16384 + (wn * 64 + lr) * 64;    // + cf*1024 (+2048 for n-sub 1)

  f32x4 acc[8][4];
#pragma unroll
  for (int i = 0; i < 8; ++i)
#pragma unroll
    for (int j = 0; j < 4; ++j) acc[i][j] = (f32x4){0.f, 0.f, 0.f, 0.f};

  // prologue: t0 full (8 loads) + B(1) (4 loads); vmcnt(4) => t0 landed
  STAGE(0, 0, 0) STAGE(1, 0, 0) STAGE(0, 0, 1) STAGE(1, 0, 1)
  STAGE(0, 1, 1) STAGE(1, 1, 1)
  asm volatile("s_waitcnt vmcnt(4)" ::: "memory");
  __builtin_amdgcn_s_barrier();

  bf16x8 af[4][2], b0f[2][2], b1f[2][2];
  for (int t = 0; t < NT64; ++t) {
    const int bb = (t & 1) * 32768;
    // ---- P1: ds_read A(rows wm*128+0..63) + B-sub0; stage A0(t+1); MFMA (m0,n0) ----
#pragma unroll
    for (int rf = 0; rf < 4; ++rf) {
      af[rf][0] = *(const bf16x8*)&smem[bb + arow + rf * 1024 + chunk0];
      af[rf][1] = *(const bf16x8*)&smem[bb + arow + rf * 1024 + chunk1];
    }
#pragma unroll
    for (int cf = 0; cf < 2; ++cf) {
      b0f[cf][0] = *(const bf16x8*)&smem[bb + brow + cf * 1024 + chunk0];
      b0f[cf][1] = *(const bf16x8*)&smem[bb + brow + cf * 1024 + chunk1];
    }
    if (t + 1 < NT64) STAGE(0, t + 1, 0)
    __builtin_amdgcn_s_setprio(1);
#pragma unroll
    for (int rf = 0; rf < 4; ++rf)
#pragma unroll
      for (int cf = 0; cf < 2; ++cf)
#pragma unroll
        for (int kh = 0; kh < 2; ++kh)
          acc[rf][cf] = __builtin_amdgcn_mfma_f32_16x16x32_bf16(af[rf][kh], b0f[cf][kh], acc[rf][cf], 0, 0, 0);
    __builtin_amdgcn_s_setprio(0);
    asm volatile("" ::: "memory");
    __builtin_amdgcn_s_barrier();
    // ---- P2: ds_read B-sub1; stage A1(t+1); MFMA (m0,n1) ----
#pragma unroll
    for (int cf = 0; cf < 2; ++cf) {
      b1f[cf][0] = *(const bf16x8*)&smem[bb + brow + 2048 + cf * 1024 + chunk0];
      b1f[cf][1] = *(const bf16x8*)&smem[bb + brow + 2048 + cf * 1024 + chunk1];
    }
    if (t + 1 < NT64) STAGE(1, t + 1, 0)
    __builtin_amdgcn_s_setprio(1);
#pragma unroll
    for (int rf = 0; rf < 4; ++rf)
#pragma unroll
      for (int cf = 0; cf < 2; ++cf)
#pragma unroll
        for (int kh = 0; kh < 2; ++kh)
          acc[rf][2 + cf] = __builtin_amdgcn_mfma_f32_16x16x32_bf16(af[rf][kh], b1f[cf][kh], acc[rf][2 + cf], 0, 0, 0);
    __builtin_amdgcn_s_setprio(0);
    asm volatile("" ::: "memory");
    __builtin_amdgcn_s_barrier();
    // ---- P3: ds_read A(rows wm*128+64..127); MFMA (m1,n0) ----
#pragma unroll
    for (int rf = 0; rf < 4; ++rf) {
      af[rf][0] = *(const bf16x8*)&smem[bb + arow + 4096 + rf * 1024 + chunk0];
      af[rf][1] = *(const bf16x8*)&smem[bb + arow + 4096 + rf * 1024 + chunk1];
    }
    __builtin_amdgcn_s_setprio(1);
#pragma unroll
    for (int rf = 0; rf < 4; ++rf)
#pragma unroll
      for (int cf = 0; cf < 2; ++cf)
#pragma unroll
        for (int kh = 0; kh < 2; ++kh)
          acc[4 + rf][cf] = __builtin_amdgcn_mfma_f32_16x16x32_bf16(af[rf][kh], b0f[cf][kh], acc[4 + rf][cf], 0, 0, 0);
    __builtin_amdgcn_s_setprio(0);
    asm volatile("" ::: "memory");
    __builtin_amdgcn_s_barrier();
    // ---- P4: stage B0+B1(t+2); MFMA (m1,n1); counted vmcnt ----
    if (t + 2 < NT64) { STAGE(0, t + 2, 1) STAGE(1, t + 2, 1) }
    __builtin_amdgcn_s_setprio(1);
#pragma unroll
    for (int rf = 0; rf < 4; ++rf)
#pragma unroll
      for (int cf = 0; cf < 2; ++cf)
#pragma unroll
        for (int kh = 0; kh < 2; ++kh)
          acc[4 + rf][2 + cf] = __builtin_amdgcn_mfma_f32_16x16x32_bf16(af[rf][kh], b1f[cf][kh], acc[4 + rf][2 + cf], 0, 0, 0);
    __builtin_amdgcn_s_setprio(0);
    if (t < NT64 - 3) asm volatile("s_waitcnt vmcnt(4)" ::: "memory");
    else              asm volatile("s_waitcnt vmcnt(0)" ::: "memory");
    __builtin_amdgcn_s_barrier();
  }

  // ---- epilogue ----
  float bcol[4];
#pragma unroll
  for (int an = 0; an < 4; ++an)
    bcol[an] = bias[col0 + wn * 64 + (an >> 1) * 32 + (an & 1) * 16 + lr];

  if (OUT_MODE == 2) {
    // transposed bf16 store: KVt[(n*4+b)*4096 + s]
    const int b = row0 >> 12;
    const int s0 = (row0 & 4095) + wm * 128;
    unsigned short* wt = &smem[wave * 4096];
    unsigned short* KVt = (unsigned short*)C;
#pragma unroll
    for (int half = 0; half < 2; ++half) {
#pragma unroll
      for (int am4 = 0; am4 < 4; ++am4) {
#pragma unroll
        for (int j = 0; j < 4; ++j) {
          int r = am4 * 16 + hi * 4 + j;  // 0..63 within half
          float mrow = mask[row0 + wm * 128 + half * 64 + r];
#pragma unroll
          for (int an = 0; an < 4; ++an) {
            int c = (an >> 1) * 32 + (an & 1) * 16 + lr;
            wt[c * 64 + (r ^ ((c & 7) << 3))] =
                f2bf((acc[half * 4 + am4][an][j] + bcol[an]) * mrow);
          }
        }
      }
      asm volatile("s_waitcnt lgkmcnt(0)" ::: "memory");
#pragma unroll
      for (int i = 0; i < 8; ++i) {
        int flat = i * 64 + lane;
        int c = flat >> 3, rq = flat & 7;
        uint4 vv = *(const uint4*)&wt[c * 64 + ((rq * 8) ^ ((c & 7) << 3))];
        *(uint4*)&KVt[((size_t)(col0 + wn * 64 + c) * 4 + b) * 4096 + s0 + half * 64 + rq * 8] = vv;
      }
      asm volatile("s_waitcnt lgkmcnt(0)" ::: "memory");
    }
  } else {
    // OUT_MODE 4: fused q @ kv_head -> f32 out
    float* Og = (float*)C;
    const int b = row0 >> 12;
    const int bh = b * 16 + (col0 >> 6) + wn;  // this wave's head
    unsigned short* wt = &smem[wave * 4096];
    // kv B-frags (global; kvt is 512 KB, L2-hot)
    bf16x8 kvf[4][2];
#pragma unroll
    for (int et = 0; et < 4; ++et) {
      kvf[et][0] = *(const bf16x8*)&kvt[(size_t)bh * 4096 + (et * 16 + lr) * 64 + hi * 8];
      kvf[et][1] = *(const bf16x8*)&kvt[(size_t)bh * 4096 + (et * 16 + lr) * 64 + 32 + hi * 8];
    }
#pragma unroll
    for (int half = 0; half < 2; ++half) {
#pragma unroll
      for (int am4 = 0; am4 < 4; ++am4) {
#pragma unroll
        for (int j = 0; j < 4; ++j) {
          int r = am4 * 16 + hi * 4 + j;  // 0..63 within half
          float mrow = mask[row0 + wm * 128 + half * 64 + r];
#pragma unroll
          for (int an = 0; an < 4; ++an) {
            int c = (an >> 1) * 32 + (an & 1) * 16 + lr;
            wt[r * 64 + (c ^ ((r & 7) << 3))] =
                f2bf((acc[half * 4 + am4][an][j] + bcol[an]) * mrow);
          }
        }
      }
      asm volatile("s_waitcnt lgkmcnt(0)" ::: "memory");
      // q A-frags from wt (same swizzle as K-loop), multiply by kv
      f32x4 oacc[4][4];
#pragma unroll
      for (int g = 0; g < 4; ++g) {
        bf16x8 a0 = *(const bf16x8*)&wt[(g * 16 + lr) * 64 + chunk0];
        bf16x8 a1 = *(const bf16x8*)&wt[(g * 16 + lr) * 64 + chunk1];
#pragma unroll
        for (int et = 0; et < 4; ++et) {
          oacc[g][et] = (f32x4){0.f, 0.f, 0.f, 0.f};
          oacc[g][et] = __builtin_amdgcn_mfma_f32_16x16x32_bf16(a0, kvf[et][0], oacc[g][et], 0, 0, 0);
          oacc[g][et] = __builtin_amdgcn_mfma_f32_16x16x32_bf16(a1, kvf[et][1], oacc[g][et], 0, 0, 0);
        }
      }
#pragma unroll
      for (int g = 0; g < 4; ++g)
#pragma unroll
        for (int et = 0; et < 4; ++et)
#pragma unroll
          for (int j = 0; j < 4; ++j)
            __builtin_nontemporal_store(oacc[g][et][j],
                &Og[(size_t)(row0 + wm * 128 + half * 64 + g * 16 + hi * 4 + j) * 1024
                    + col0 + wn * 64 + et * 16 + lr]);
      asm volatile("s_waitcnt lgkmcnt(0)" ::: "memory");
    }
  }
#undef STAGE
}

// ---------------- kv partials via MFMA: part[ch][bh][d][e] = sum_s Kt[d][s]*Vt[e][s] ----
__global__ __launch_bounds__(256) void kvpart2_k(const unsigned short* __restrict__ KVt,
                                                 float* __restrict__ part) {
  const int bh = blockIdx.x, ch = blockIdx.y;
  const int b = bh >> 4, h = bh & 15;
  __shared__ unsigned short tl[32768];  // 4 bufs x (A[64][64] + B[64][64]) = 64 KiB
  const int tid = threadIdx.x;
  const int wave = tid >> 6, lane = tid & 63;
  const int lr = lane & 15, hi = lane >> 4;

  const int r0 = tid >> 3;
  const int cc0 = ((tid & 7) ^ (r0 & 7)) * 8;
  const int r1 = 32 + r0;
  const int cc1 = ((tid & 7) ^ (r1 & 7)) * 8;
  const unsigned short* A0 = KVt + ((size_t)(h * 64 + r0) * 4 + b) * 4096 + ch * 1024 + cc0;
  const unsigned short* A1 = KVt + ((size_t)(h * 64 + r1) * 4 + b) * 4096 + ch * 1024 + cc1;
  const unsigned short* B0 = KVt + ((size_t)(1024 + h * 64 + r0) * 4 + b) * 4096 + ch * 1024 + cc0;
  const unsigned short* B1 = KVt + ((size_t)(1024 + h * 64 + r1) * 4 + b) * 4096 + ch * 1024 + cc1;

#define KSTAGE(tt) { int bb2 = ((tt) & 3) * 8192; \
    load_lds16(A0 + (tt) * 64, &tl[bb2 + tid * 8]); \
    load_lds16(A1 + (tt) * 64, &tl[bb2 + 2048 + tid * 8]); \
    load_lds16(B0 + (tt) * 64, &tl[bb2 + 4096 + tid * 8]); \
    load_lds16(B1 + (tt) * 64, &tl[bb2 + 6144 + tid * 8]); }

  const int ra = wave * 16 + lr;
  const int aoff = ra * 64;
  const int ach0 = (hi ^ (ra & 7)) * 8, ach1 = ((4 + hi) ^ (ra & 7)) * 8;

  f32x4 acc4[4];
#pragma unroll
  for (int nt = 0; nt < 4; ++nt) acc4[nt] = (f32x4){0.f, 0.f, 0.f, 0.f};

  KSTAGE(0) KSTAGE(1)
  asm volatile("s_waitcnt vmcnt(4)" ::: "memory");
  __builtin_amdgcn_s_barrier();
  for (int t = 0; t < 16; ++t) {
    const int bb = (t & 3) * 8192;
    if (t + 2 < 16) KSTAGE(t + 2)
    bf16x8 a0 = *(const bf16x8*)&tl[bb + aoff + ach0];
    bf16x8 a1 = *(const bf16x8*)&tl[bb + aoff + ach1];
    bf16x8 bf0[4], bf1[4];
#pragma unroll
    for (int nt = 0; nt < 4; ++nt) {
      int rb = nt * 16 + lr;
      bf0[nt] = *(const bf16x8*)&tl[bb + 4096 + rb * 64 + ((hi ^ (rb & 7)) * 8)];
      bf1[nt] = *(const bf16x8*)&tl[bb + 4096 + rb * 64 + (((4 + hi) ^ (rb & 7)) * 8)];
    }
#pragma unroll
    for (int nt = 0; nt < 4; ++nt) {
      acc4[nt] = __builtin_amdgcn_mfma_f32_16x16x32_bf16(a0, bf0[nt], acc4[nt], 0, 0, 0);
      acc4[nt] = __builtin_amdgcn_mfma_f32_16x16x32_bf16(a1, bf1[nt], acc4[nt], 0, 0, 0);
    }
    if (t < 14) asm volatile("s_waitcnt vmcnt(4)" ::: "memory");
    else        asm volatile("s_waitcnt vmcnt(0)" ::: "memory");
    __builtin_amdgcn_s_barrier();
  }
  float* dst = part + ((size_t)(ch * 64 + bh)) * 4096;
#pragma unroll
  for (int nt = 0; nt < 4; ++nt)
#pragma unroll
    for (int j = 0; j < 4; ++j)
      dst[(wave * 16 + hi * 4 + j) * 64 + nt * 16 + lr] = acc4[nt][j];
#undef KSTAGE
}

// ---------------- reduce + transpose + norm: kvt[bh][e][d] bf16 ----------------
__global__ void kvreduce_k(const float* __restrict__ part, const float* __restrict__ norm,
                           unsigned short* __restrict__ kvt) {
  int idx4 = (blockIdx.x * 256 + threadIdx.x) * 4;  // [bh][e][d0..d0+3]
  int bh = idx4 >> 12, rem = idx4 & 4095;
  int e = rem >> 6, d0 = rem & 63;
  float s0 = 0.f, s1 = 0.f, s2 = 0.f, s3 = 0.f;
#pragma unroll
  for (int ch = 0; ch < NCH; ++ch) {
    const float* p = part + ((size_t)(ch * 64 + bh)) * 4096 + e;  // [d][e] layout
    s0 += p[(d0 + 0) * 64];
    s1 += p[(d0 + 1) * 64];
    s2 += p[(d0 + 2) * 64];
    s3 += p[(d0 + 3) * 64];
  }
  float nb = norm[bh >> 4];
  ushort4 o;
  o.x = f2bf(s0 * nb); o.y = f2bf(s1 * nb); o.z = f2bf(s2 * nb); o.w = f2bf(s3 * nb);
  *(ushort4*)&kvt[idx4] = o;
}

// ---------------- launch ----------------
extern "C" void kernel_launch(void* const* d_in, const int* in_sizes, int n_in,
                              void* d_out, int out_size, void* d_ws, size_t ws_size,
                              hipStream_t stream) {
  const float* x = (const float*)d_in[0];
  const float* mask = (const float*)d_in[1];
  const float* Wq = (const float*)d_in[2];
  const float* bq = (const float*)d_in[3];
  const float* Wk = (const float*)d_in[4];
  const float* bk = (const float*)d_in[5];
  const float* Wv = (const float*)d_in[6];
  const float* bv = (const float*)d_in[7];
  float* out = (float*)d_out;

  char* w = (char*)d_ws;
  unsigned short* xb = (unsigned short*)w;   w += (size_t)M_TOT * HIDDEN * 2;       // 32 MiB
  unsigned short* Bt = (unsigned short*)w;   w += (size_t)2048 * HIDDEN * 2;        // 4 MiB
  unsigned short* Wqt = (unsigned short*)w;  w += (size_t)HIDDEN * HIDDEN * 2;      // 2 MiB
  unsigned short* KVt = (unsigned short*)w;  w += (size_t)2048 * BATCH * SEQ * 2;   // 64 MiB
  float* part = (float*)w;                   w += (size_t)NCH * 64 * 4096 * 4;      // 4 MiB
  unsigned short* kvt = (unsigned short*)w;  w += (size_t)64 * 4096 * 2;            // 0.5 MiB
  float* bkv = (float*)w;                    w += 2048 * 4;
  float* norm = (float*)w;                   w += 64;

  prep_k<<<dim3(8972), dim3(256), 0, stream>>>(x, xb, Wk, Wv, Wq, Bt, Wqt, bk, bv, bkv, mask, norm);
  // KV projection: M=16384, N=2048 -> 512 blocks; writes transposed KVt
  gemm256_k<2><<<dim3(512), dim3(512), 0, stream>>>(xb, Bt, bkv, mask, nullptr, (void*)KVt, 8);
  kvpart2_k<<<dim3(64, NCH), dim3(256), 0, stream>>>(KVt, part);
  kvreduce_k<<<dim3(256), dim3(256), 0, stream>>>(part, norm, kvt);
  // Fused Q projection + out = q @ kv_head: M=16384, N=1024 -> 256 blocks; f32 out
  gemm256_k<4><<<dim3(256), dim3(512), 0, stream>>>(xb, Wqt, bq, mask, kvt, (void*)out, 4);
}

// Round 16
// 150.997 us; speedup vs baseline: 1.7501x; 1.0226x over previous
//
#include <hip/hip_runtime.h>
#include <stdint.h>

#define HIDDEN 1024
#define SEQ 4096
#define BATCH 4
#define HEADS 16
#define HDIM 64
#define M_TOT (BATCH * SEQ)   // 16384
#define NCH 4                 // split-S chunks for kv reduction
#define NT64 16               // K-steps of 64 in projection GEMMs

typedef __bf16 bf16x8 __attribute__((ext_vector_type(8)));
typedef float f32x4 __attribute__((ext_vector_type(4)));
typedef unsigned short u16x8 __attribute__((ext_vector_type(8)));

static __device__ __forceinline__ unsigned short f2bf(float f) {
  union { float f; uint32_t u; } v; v.f = f;
  uint32_t u = v.u;
  uint32_t r = (u + 0x7fffu + ((u >> 16) & 1u)) >> 16;
  return (unsigned short)r;
}
static __device__ __forceinline__ void load_lds16(const void* g, void* l) {
  __builtin_amdgcn_global_load_lds(
      (__attribute__((address_space(1))) void*)(g),
      (__attribute__((address_space(3))) void*)(l), 16, 0, 0);
}

// ---------------- fused prep kernel ----------------
// [0,8192): x f32->bf16; [8192,8960): transpose Wk/Wv/Wq -> Bt|Wqt;
// [8960,8968): bias concat bk|bv; [8968,8972): mask sum -> norm
__global__ __launch_bounds__(256) void prep_k(
    const float* __restrict__ x, unsigned short* __restrict__ xb,
    const float* __restrict__ Wk, const float* __restrict__ Wv,
    const float* __restrict__ Wq,
    unsigned short* __restrict__ Bt, unsigned short* __restrict__ Wqt,
    const float* __restrict__ bk, const float* __restrict__ bv,
    float* __restrict__ bkv,
    const float* __restrict__ mask, float* __restrict__ norm) {
  const int bid = blockIdx.x;
  const int tid = threadIdx.x;
  __shared__ float ts[64][65];
  if (bid < 8192) {
    int idx = bid * 256 + tid;
    const float4* xv = (const float4*)x;
    float4 a = xv[(size_t)idx * 2];
    float4 b = xv[(size_t)idx * 2 + 1];
    u16x8 o;
    o[0] = f2bf(a.x); o[1] = f2bf(a.y); o[2] = f2bf(a.z); o[3] = f2bf(a.w);
    o[4] = f2bf(b.x); o[5] = f2bf(b.y); o[6] = f2bf(b.z); o[7] = f2bf(b.w);
    *(u16x8*)(xb + (size_t)idx * 8) = o;
  } else if (bid < 8960) {
    int idx = bid - 8192;
    int z = idx >> 8, rem = idx & 255;
    const float* W = (z == 0) ? Wk : (z == 1) ? Wv : Wq;
    unsigned short* out = (z == 2) ? Wqt : (Bt + (size_t)z * HIDDEN * HIDDEN);
    int n0 = (rem & 15) * 64, k0 = (rem >> 4) * 64;
    int c = tid & 63, rq = tid >> 6;
    for (int i = 0; i < 16; ++i) {
      int r = i * 4 + rq;
      ts[r][c] = W[(size_t)(k0 + r) * HIDDEN + n0 + c];
    }
    __syncthreads();
    for (int i = 0; i < 16; ++i) {
      int n = i * 4 + rq;
      out[(size_t)(n0 + n) * HIDDEN + k0 + c] = f2bf(ts[c][n]);
    }
  } else if (bid < 8968) {
    int i = (bid - 8960) * 256 + tid;
    bkv[i] = (i < HIDDEN) ? bk[i] : bv[i - HIDDEN];
  } else {
    int b = bid - 8968;
    float s = 0.f;
    for (int i = tid; i < SEQ; i += 256) s += mask[b * SEQ + i];
    for (int off = 32; off; off >>= 1) s += __shfl_down(s, off);
    __shared__ float wsum[4];
    if ((tid & 63) == 0) wsum[tid >> 6] = s;
    __syncthreads();
    if (tid == 0) {
      float t = wsum[0] + wsum[1] + wsum[2] + wsum[3];
      norm[b] = rsqrtf(t * (float)HDIM);
    }
  }
}

// ---------------- 256x256 GEMM (R6 core) ----------------
// C[row][n] = sum_k A[row][k]*Bt[n][k] + bias[n], then * mask[row].
// OUT_MODE 2: bf16 transposed KVt[(n*4+b)*4096+s].
// OUT_MODE 4: FUSED out = ((xWq+bq)*mask) @ kv_head  -> f32 row-major out,
//   with output restaged through upper-LDS for coalesced 16B stores.
template <int OUT_MODE>
__global__ __launch_bounds__(512, 2) void gemm256_k(
    const unsigned short* __restrict__ A, const unsigned short* __restrict__ Bt,
    const float* __restrict__ bias, const float* __restrict__ mask,
    const unsigned short* __restrict__ kvt,
    void* __restrict__ C, int nbn) {
  __shared__ unsigned short smem[65536];  // 128 KiB: 2 bufs x (A 256x64 + B 256x64)

  const int nwg = gridDim.x;
  const int bid = blockIdx.x;
  const int wg = (bid & 7) * (nwg >> 3) + (bid >> 3);  // XCD swizzle (nwg%8==0)
  const int row0 = (wg / nbn) * 256;
  const int col0 = (wg % nbn) * 256;

  const int tid = threadIdx.x;
  const int wave = tid >> 6;
  const int lane = tid & 63;
  const int wm = wave >> 2;   // 0..1 (M half)
  const int wn = wave & 3;    // 0..3 (N quarter)
  const int lr = lane & 15;
  const int hi = lane >> 4;   // 0..3

  // staging: linear LDS dest, inverse-swizzled global source (chunk ^= row&7)
  const int srow = tid >> 3;                        // 0..63
  const int scol = ((tid & 7) ^ (srow & 7)) * 8;    // (row&7)-XORed 16B chunk
  const unsigned short* sA = A + (size_t)(row0 + srow) * HIDDEN + scol;
  const unsigned short* sB = Bt + (size_t)(col0 + srow) * HIDDEN + scol;
  const int ldst = tid * 8;

#define STAGE(half, tt, isB) { \
    int dst_ = ((tt)&1) * 32768 + (isB) * 16384 + (half) * 8192 + ldst; \
    const unsigned short* src_ = ((isB) ? sB : sA) + (size_t)(half) * 128 * HIDDEN + (tt) * 64; \
    load_lds16(src_, &smem[dst_]); \
    load_lds16(src_ + (size_t)64 * HIDDEN, &smem[dst_ + 4096]); }

  // swizzled frag read offsets: row ra -> ra*64 + ((k8 ^ (ra&7))*8); ra&7 == lr&7
  const int chunk0 = (hi ^ (lr & 7)) * 8;          // kh=0
  const int chunk1 = ((4 + hi) ^ (lr & 7)) * 8;    // kh=1
  const int arow = (wm * 128 + lr) * 64;           // + rf*1024 (+4096 for m-half 1)
  const int brow = 16384 + (wn * 64 + lr) * 64;    // + cf*1024 (+2048 for n-sub 1)

  f32x4 acc[8][4];
#pragma unroll
  for (int i = 0; i < 8; ++i)
#pragma unroll
    for (int j = 0; j < 4; ++j) acc[i][j] = (f32x4){0.f, 0.f, 0.f, 0.f};

  // prologue: t0 full (8 loads) + B(1) (4 loads); vmcnt(4) => t0 landed
  STAGE(0, 0, 0) STAGE(1, 0, 0) STAGE(0, 0, 1) STAGE(1, 0, 1)
  STAGE(0, 1, 1) STAGE(1, 1, 1)
  asm volatile("s_waitcnt vmcnt(4)" ::: "memory");
  __builtin_amdgcn_s_barrier();

  bf16x8 af[4][2], b0f[2][2], b1f[2][2];
  for (int t = 0; t < NT64; ++t) {
    const int bb = (t & 1) * 32768;
    // ---- P1: ds_read A(rows wm*128+0..63) + B-sub0; stage A0(t+1); MFMA (m0,n0) ----
#pragma unroll
    for (int rf = 0; rf < 4; ++rf) {
      af[rf][0] = *(const bf16x8*)&smem[bb + arow + rf * 1024 + chunk0];
      af[rf][1] = *(const bf16x8*)&smem[bb + arow + rf * 1024 + chunk1];
    }
#pragma unroll
    for (int cf = 0; cf < 2; ++cf) {
      b0f[cf][0] = *(const bf16x8*)&smem[bb + brow + cf * 1024 + chunk0];
      b0f[cf][1] = *(const bf16x8*)&smem[bb + brow + cf * 1024 + chunk1];
    }
    if (t + 1 < NT64) STAGE(0, t + 1, 0)
    __builtin_amdgcn_s_setprio(1);
#pragma unroll
    for (int rf = 0; rf < 4; ++rf)
#pragma unroll
      for (int cf = 0; cf < 2; ++cf)
#pragma unroll
        for (int kh = 0; kh < 2; ++kh)
          acc[rf][cf] = __builtin_amdgcn_mfma_f32_16x16x32_bf16(af[rf][kh], b0f[cf][kh], acc[rf][cf], 0, 0, 0);
    __builtin_amdgcn_s_setprio(0);
    asm volatile("" ::: "memory");
    __builtin_amdgcn_s_barrier();
    // ---- P2: ds_read B-sub1; stage A1(t+1); MFMA (m0,n1) ----
#pragma unroll
    for (int cf = 0; cf < 2; ++cf) {
      b1f[cf][0] = *(const bf16x8*)&smem[bb + brow + 2048 + cf * 1024 + chunk0];
      b1f[cf][1] = *(const bf16x8*)&smem[bb + brow + 2048 + cf * 1024 + chunk1];
    }
    if (t + 1 < NT64) STAGE(1, t + 1, 0)
    __builtin_amdgcn_s_setprio(1);
#pragma unroll
    for (int rf = 0; rf < 4; ++rf)
#pragma unroll
      for (int cf = 0; cf < 2; ++cf)
#pragma unroll
        for (int kh = 0; kh < 2; ++kh)
          acc[rf][2 + cf] = __builtin_amdgcn_mfma_f32_16x16x32_bf16(af[rf][kh], b1f[cf][kh], acc[rf][2 + cf], 0, 0, 0);
    __builtin_amdgcn_s_setprio(0);
    asm volatile("" ::: "memory");
    __builtin_amdgcn_s_barrier();
    // ---- P3: ds_read A(rows wm*128+64..127); MFMA (m1,n0) ----
#pragma unroll
    for (int rf = 0; rf < 4; ++rf) {
      af[rf][0] = *(const bf16x8*)&smem[bb + arow + 4096 + rf * 1024 + chunk0];
      af[rf][1] = *(const bf16x8*)&smem[bb + arow + 4096 + rf * 1024 + chunk1];
    }
    __builtin_amdgcn_s_setprio(1);
#pragma unroll
    for (int rf = 0; rf < 4; ++rf)
#pragma unroll
      for (int cf = 0; cf < 2; ++cf)
#pragma unroll
        for (int kh = 0; kh < 2; ++kh)
          acc[4 + rf][cf] = __builtin_amdgcn_mfma_f32_16x16x32_bf16(af[rf][kh], b0f[cf][kh], acc[4 + rf][cf], 0, 0, 0);
    __builtin_amdgcn_s_setprio(0);
    asm volatile("" ::: "memory");
    __builtin_amdgcn_s_barrier();
    // ---- P4: stage B0+B1(t+2); MFMA (m1,n1); counted vmcnt ----
    if (t + 2 < NT64) { STAGE(0, t + 2, 1) STAGE(1, t + 2, 1) }
    __builtin_amdgcn_s_setprio(1);
#pragma unroll
    for (int rf = 0; rf < 4; ++rf)
#pragma unroll
      for (int cf = 0; cf < 2; ++cf)
#pragma unroll
        for (int kh = 0; kh < 2; ++kh)
          acc[4 + rf][2 + cf] = __builtin_amdgcn_mfma_f32_16x16x32_bf16(af[rf][kh], b1f[cf][kh], acc[4 + rf][2 + cf], 0, 0, 0);
    __builtin_amdgcn_s_setprio(0);
    if (t < NT64 - 3) asm volatile("s_waitcnt vmcnt(4)" ::: "memory");
    else              asm volatile("s_waitcnt vmcnt(0)" ::: "memory");
    __builtin_amdgcn_s_barrier();
  }

  // ---- epilogue ----
  float bcol[4];
#pragma unroll
  for (int an = 0; an < 4; ++an)
    bcol[an] = bias[col0 + wn * 64 + (an >> 1) * 32 + (an & 1) * 16 + lr];

  if (OUT_MODE == 2) {
    // transposed bf16 store: KVt[(n*4+b)*4096 + s]
    const int b = row0 >> 12;
    const int s0 = (row0 & 4095) + wm * 128;
    unsigned short* wt = &smem[wave * 4096];
    unsigned short* KVt = (unsigned short*)C;
#pragma unroll
    for (int half = 0; half < 2; ++half) {
#pragma unroll
      for (int am4 = 0; am4 < 4; ++am4) {
#pragma unroll
        for (int j = 0; j < 4; ++j) {
          int r = am4 * 16 + hi * 4 + j;  // 0..63 within half
          float mrow = mask[row0 + wm * 128 + half * 64 + r];
#pragma unroll
          for (int an = 0; an < 4; ++an) {
            int c = (an >> 1) * 32 + (an & 1) * 16 + lr;
            wt[c * 64 + (r ^ ((c & 7) << 3))] =
                f2bf((acc[half * 4 + am4][an][j] + bcol[an]) * mrow);
          }
        }
      }
      asm volatile("s_waitcnt lgkmcnt(0)" ::: "memory");
#pragma unroll
      for (int i = 0; i < 8; ++i) {
        int flat = i * 64 + lane;
        int c = flat >> 3, rq = flat & 7;
        uint4 vv = *(const uint4*)&wt[c * 64 + ((rq * 8) ^ ((c & 7) << 3))];
        *(uint4*)&KVt[((size_t)(col0 + wn * 64 + c) * 4 + b) * 4096 + s0 + half * 64 + rq * 8] = vv;
      }
      asm volatile("s_waitcnt lgkmcnt(0)" ::: "memory");
    }
  } else {
    // OUT_MODE 4: fused q @ kv_head -> f32 out (coalesced via upper-LDS restage)
    float* Og = (float*)C;
    const int b = row0 >> 12;
    const int bh = b * 16 + (col0 >> 6) + wn;  // this wave's head
    unsigned short* wt = &smem[wave * 4096];              // lower 32 KB: q bf16 restage
    float* wf = (float*)&smem[32768 + wave * 4096];       // upper 32 KB: 32x64 f32 out
    // kv B-frags (global; kvt is 512 KB, L2-hot)
    bf16x8 kvf[4][2];
#pragma unroll
    for (int et = 0; et < 4; ++et) {
      kvf[et][0] = *(const bf16x8*)&kvt[(size_t)bh * 4096 + (et * 16 + lr) * 64 + hi * 8];
      kvf[et][1] = *(const bf16x8*)&kvt[(size_t)bh * 4096 + (et * 16 + lr) * 64 + 32 + hi * 8];
    }
#pragma unroll
    for (int half = 0; half < 2; ++half) {
#pragma unroll
      for (int am4 = 0; am4 < 4; ++am4) {
#pragma unroll
        for (int j = 0; j < 4; ++j) {
          int r = am4 * 16 + hi * 4 + j;  // 0..63 within half
          float mrow = mask[row0 + wm * 128 + half * 64 + r];
#pragma unroll
          for (int an = 0; an < 4; ++an) {
            int c = (an >> 1) * 32 + (an & 1) * 16 + lr;
            wt[r * 64 + (c ^ ((r & 7) << 3))] =
                f2bf((acc[half * 4 + am4][an][j] + bcol[an]) * mrow);
          }
        }
      }
      asm volatile("s_waitcnt lgkmcnt(0)" ::: "memory");
      // q A-frags from wt (same swizzle as K-loop), multiply by kv
      f32x4 oacc[4][4];
#pragma unroll
      for (int g = 0; g < 4; ++g) {
        bf16x8 a0 = *(const bf16x8*)&wt[(g * 16 + lr) * 64 + chunk0];
        bf16x8 a1 = *(const bf16x8*)&wt[(g * 16 + lr) * 64 + chunk1];
#pragma unroll
        for (int et = 0; et < 4; ++et) {
          oacc[g][et] = (f32x4){0.f, 0.f, 0.f, 0.f};
          oacc[g][et] = __builtin_amdgcn_mfma_f32_16x16x32_bf16(a0, kvf[et][0], oacc[g][et], 0, 0, 0);
          oacc[g][et] = __builtin_amdgcn_mfma_f32_16x16x32_bf16(a1, kvf[et][1], oacc[g][et], 0, 0, 0);
        }
      }
      // restage through wf (32 rows at a time) -> fully coalesced 16B f32x4 stores
#pragma unroll
      for (int gp = 0; gp < 2; ++gp) {
#pragma unroll
        for (int g2 = 0; g2 < 2; ++g2) {
          int g = gp * 2 + g2;
#pragma unroll
          for (int et = 0; et < 4; ++et)
#pragma unroll
            for (int j = 0; j < 4; ++j)
              wf[(g2 * 16 + hi * 4 + j) * 64 + et * 16 + lr] = oacc[g][et][j];
        }
        asm volatile("s_waitcnt lgkmcnt(0)" ::: "memory");
#pragma unroll
        for (int i = 0; i < 8; ++i) {
          int flat = i * 256 + lane * 4;       // f32 index within 32x64 tile
          int r2 = flat >> 6, c2 = flat & 63;
          f32x4 vv = *(const f32x4*)&wf[flat];
          __builtin_nontemporal_store(vv,
              (f32x4*)&Og[(size_t)(row0 + wm * 128 + half * 64 + gp * 32 + r2) * 1024
                          + col0 + wn * 64 + c2]);
        }
        asm volatile("s_waitcnt lgkmcnt(0)" ::: "memory");
      }
      asm volatile("s_waitcnt lgkmcnt(0)" ::: "memory");
    }
  }
#undef STAGE
}

// ---------------- kv partials via MFMA: part[ch][bh][d][e] = sum_s Kt[d][s]*Vt[e][s] ----
__global__ __launch_bounds__(256) void kvpart2_k(const unsigned short* __restrict__ KVt,
                                                 float* __restrict__ part) {
  const int bh = blockIdx.x, ch = blockIdx.y;
  const int b = bh >> 4, h = bh & 15;
  __shared__ unsigned short tl[32768];  // 4 bufs x (A[64][64] + B[64][64]) = 64 KiB
  const int tid = threadIdx.x;
  const int wave = tid >> 6, lane = tid & 63;
  const int lr = lane & 15, hi = lane >> 4;

  const int r0 = tid >> 3;
  const int cc0 = ((tid & 7) ^ (r0 & 7)) * 8;
  const int r1 = 32 + r0;
  const int cc1 = ((tid & 7) ^ (r1 & 7)) * 8;
  const unsigned short* A0 = KVt + ((size_t)(h * 64 + r0) * 4 + b) * 4096 + ch * 1024 + cc0;
  const unsigned short* A1 = KVt + ((size_t)(h * 64 + r1) * 4 + b) * 4096 + ch * 1024 + cc1;
  const unsigned short* B0 = KVt + ((size_t)(1024 + h * 64 + r0) * 4 + b) * 4096 + ch * 1024 + cc0;
  const unsigned short* B1 = KVt + ((size_t)(1024 + h * 64 + r1) * 4 + b) * 4096 + ch * 1024 + cc1;

#define KSTAGE(tt) { int bb2 = ((tt) & 3) * 8192; \
    load_lds16(A0 + (tt) * 64, &tl[bb2 + tid * 8]); \
    load_lds16(A1 + (tt) * 64, &tl[bb2 + 2048 + tid * 8]); \
    load_lds16(B0 + (tt) * 64, &tl[bb2 + 4096 + tid * 8]); \
    load_lds16(B1 + (tt) * 64, &tl[bb2 + 6144 + tid * 8]); }

  const int ra = wave * 16 + lr;
  const int aoff = ra * 64;
  const int ach0 = (hi ^ (ra & 7)) * 8, ach1 = ((4 + hi) ^ (ra & 7)) * 8;

  f32x4 acc4[4];
#pragma unroll
  for (int nt = 0; nt < 4; ++nt) acc4[nt] = (f32x4){0.f, 0.f, 0.f, 0.f};

  KSTAGE(0) KSTAGE(1)
  asm volatile("s_waitcnt vmcnt(4)" ::: "memory");
  __builtin_amdgcn_s_barrier();
  for (int t = 0; t < 16; ++t) {
    const int bb = (t & 3) * 8192;
    if (t + 2 < 16) KSTAGE(t + 2)
    bf16x8 a0 = *(const bf16x8*)&tl[bb + aoff + ach0];
    bf16x8 a1 = *(const bf16x8*)&tl[bb + aoff + ach1];
    bf16x8 bf0[4], bf1[4];
#pragma unroll
    for (int nt = 0; nt < 4; ++nt) {
      int rb = nt * 16 + lr;
      bf0[nt] = *(const bf16x8*)&tl[bb + 4096 + rb * 64 + ((hi ^ (rb & 7)) * 8)];
      bf1[nt] = *(const bf16x8*)&tl[bb + 4096 + rb * 64 + (((4 + hi) ^ (rb & 7)) * 8)];
    }
#pragma unroll
    for (int nt = 0; nt < 4; ++nt) {
      acc4[nt] = __builtin_amdgcn_mfma_f32_16x16x32_bf16(a0, bf0[nt], acc4[nt], 0, 0, 0);
      acc4[nt] = __builtin_amdgcn_mfma_f32_16x16x32_bf16(a1, bf1[nt], acc4[nt], 0, 0, 0);
    }
    if (t < 14) asm volatile("s_waitcnt vmcnt(4)" ::: "memory");
    else        asm volatile("s_waitcnt vmcnt(0)" ::: "memory");
    __builtin_amdgcn_s_barrier();
  }
  float* dst = part + ((size_t)(ch * 64 + bh)) * 4096;
#pragma unroll
  for (int nt = 0; nt < 4; ++nt)
#pragma unroll
    for (int j = 0; j < 4; ++j)
      dst[(wave * 16 + hi * 4 + j) * 64 + nt * 16 + lr] = acc4[nt][j];
#undef KSTAGE
}

// ---------------- reduce + transpose + norm: kvt[bh][e][d] bf16 ----------------
__global__ void kvreduce_k(const float* __restrict__ part, const float* __restrict__ norm,
                           unsigned short* __restrict__ kvt) {
  int idx4 = (blockIdx.x * 256 + threadIdx.x) * 4;  // [bh][e][d0..d0+3]
  int bh = idx4 >> 12, rem = idx4 & 4095;
  int e = rem >> 6, d0 = rem & 63;
  float s0 = 0.f, s1 = 0.f, s2 = 0.f, s3 = 0.f;
#pragma unroll
  for (int ch = 0; ch < NCH; ++ch) {
    const float* p = part + ((size_t)(ch * 64 + bh)) * 4096 + e;  // [d][e] layout
    s0 += p[(d0 + 0) * 64];
    s1 += p[(d0 + 1) * 64];
    s2 += p[(d0 + 2) * 64];
    s3 += p[(d0 + 3) * 64];
  }
  float nb = norm[bh >> 4];
  ushort4 o;
  o.x = f2bf(s0 * nb); o.y = f2bf(s1 * nb); o.z = f2bf(s2 * nb); o.w = f2bf(s3 * nb);
  *(ushort4*)&kvt[idx4] = o;
}

// ---------------- launch ----------------
extern "C" void kernel_launch(void* const* d_in, const int* in_sizes, int n_in,
                              void* d_out, int out_size, void* d_ws, size_t ws_size,
                              hipStream_t stream) {
  const float* x = (const float*)d_in[0];
  const float* mask = (const float*)d_in[1];
  const float* Wq = (const float*)d_in[2];
  const float* bq = (const float*)d_in[3];
  const float* Wk = (const float*)d_in[4];
  const float* bk = (const float*)d_in[5];
  const float* Wv = (const float*)d_in[6];
  const float* bv = (const float*)d_in[7];
  float* out = (float*)d_out;

  char* w = (char*)d_ws;
  unsigned short* xb = (unsigned short*)w;   w += (size_t)M_TOT * HIDDEN * 2;       // 32 MiB
  unsigned short* Bt = (unsigned short*)w;   w += (size_t)2048 * HIDDEN * 2;        // 4 MiB
  unsigned short* Wqt = (unsigned short*)w;  w += (size_t)HIDDEN * HIDDEN * 2;      // 2 MiB
  unsigned short* KVt = (unsigned short*)w;  w += (size_t)2048 * BATCH * SEQ * 2;   // 64 MiB
  float* part = (float*)w;                   w += (size_t)NCH * 64 * 4096 * 4;      // 4 MiB
  unsigned short* kvt = (unsigned short*)w;  w += (size_t)64 * 4096 * 2;            // 0.5 MiB
  float* bkv = (float*)w;                    w += 2048 * 4;
  float* norm = (float*)w;                   w += 64;

  prep_k<<<dim3(8972), dim3(256), 0, stream>>>(x, xb, Wk, Wv, Wq, Bt, Wqt, bk, bv, bkv, mask, norm);
  // KV projection: M=16384, N=2048 -> 512 blocks; writes transposed KVt
  gemm256_k<2><<<dim3(512), dim3(512), 0, stream>>>(xb, Bt, bkv, mask, nullptr, (void*)KVt, 8);
  kvpart2_k<<<dim3(64, NCH), dim3(256), 0, stream>>>(KVt, part);
  kvreduce_k<<<dim3(256), dim3(256), 0, stream>>>(part, norm, kvt);
  // Fused Q projection + out = q @ kv_head: M=16384, N=1024 -> 256 blocks; f32 out
  gemm256_k<4><<<dim3(256), dim3(512), 0, stream>>>(xb, Wqt, bq, mask, kvt, (void*)out, 4);
}